// Round 1
// baseline (61.419 us; speedup 1.0000x reference)
//
#include <hip/hip_runtime.h>
#include <hip/hip_bf16.h>
#include <math.h>

#define N_ROWS 8192
#define M_ROWS 4096
#define DDIM   512
#define SDIM   16

#define BM 128
#define BN 128
#define BK 64

typedef __attribute__((ext_vector_type(8))) __bf16 bf16x8;
typedef __attribute__((ext_vector_type(4))) float f32x4;

__device__ __forceinline__ unsigned short f2bf_rne(float f) {
  unsigned u = __float_as_uint(f);
  u += 0x7fffu + ((u >> 16) & 1u);
  return (unsigned short)(u >> 16);
}

__device__ __forceinline__ void load_lds16(const void* g, void* l) {
  __builtin_amdgcn_global_load_lds(
      (const __attribute__((address_space(1))) void*)g,
      (__attribute__((address_space(3))) void*)l, 16, 0, 0);
}

// One block per row (of x for row<N, of y otherwise):
//  - convert the 512-f32 row to bf16 (RNE) into workspace
//  - compute sum of squares (fp32)
//  - compute sqrt(clip(softplus(sample_row . scale)))
__global__ __launch_bounds__(256) void prep_kernel(
    const float* __restrict__ x, const float* __restrict__ y,
    const float* __restrict__ samp_x, const float* __restrict__ samp_y,
    const float* __restrict__ scale,
    ushort* __restrict__ xb, ushort* __restrict__ yb,
    float* __restrict__ sqx, float* __restrict__ sqy,
    float* __restrict__ ssx, float* __restrict__ ssy)
{
  int row = blockIdx.x;
  const float* src; const float* samp; ushort* dst; float* sqo; float* sso;
  if (row < N_ROWS) {
    src = x + (size_t)row * DDIM; samp = samp_x + (size_t)row * SDIM;
    dst = xb + (size_t)row * DDIM; sqo = sqx + row; sso = ssx + row;
  } else {
    int r = row - N_ROWS;
    src = y + (size_t)r * DDIM; samp = samp_y + (size_t)r * SDIM;
    dst = yb + (size_t)r * DDIM; sqo = sqy + r; sso = ssy + r;
  }
  int tid = threadIdx.x;  // 256 threads, 2 f32 each
  float2 v = ((const float2*)src)[tid];
  ushort2 b;
  b.x = f2bf_rne(v.x);
  b.y = f2bf_rne(v.y);
  ((ushort2*)dst)[tid] = b;
  float ss = v.x * v.x + v.y * v.y;
  #pragma unroll
  for (int off = 32; off > 0; off >>= 1) ss += __shfl_down(ss, off, 64);
  __shared__ float red[4];
  if ((tid & 63) == 0) red[tid >> 6] = ss;
  __syncthreads();
  if (tid == 0) {
    float tot = red[0] + red[1] + red[2] + red[3];
    *sqo = tot;
    float acc = 0.f;
    #pragma unroll
    for (int s = 0; s < SDIM; s++) acc += samp[s] * scale[s];
    float sp = (acc > 15.f) ? acc : log1pf(expf(acc));   // softplus, stable enough for x<=15
    sp = fminf(fmaxf(sp, 1e-10f), 10000.f);
    *sso = sqrtf(sp);
  }
}

// Fused GEMM + Cauchy epilogue.
// 128x128 tile, BK=64, 4 waves (each owns a 64x64 quadrant as 4x4 16x16 frags).
// LDS tiles stored [row][BK] row-major with XOR-swizzle applied on BOTH sides:
// the global SOURCE granule is pre-swizzled (global_load_lds writes linearly)
// and the ds_read address applies the same XOR (rule #21).
__global__ __launch_bounds__(256, 2) void cauchy_gemm(
    const ushort* __restrict__ xb, const ushort* __restrict__ yb,
    const float* __restrict__ sqx, const float* __restrict__ sqy,
    const float* __restrict__ ssx, const float* __restrict__ ssy,
    const float* __restrict__ cutoff, const float* __restrict__ phi,
    float* __restrict__ out)
{
  __shared__ ushort As[BM * BK];
  __shared__ ushort Bs[BN * BK];
  const int tid = threadIdx.x;
  const int lane = tid & 63;
  const int w = tid >> 6;
  const int wr = w >> 1, wc = w & 1;
  const int l15 = lane & 15, l16 = lane >> 4;

  const size_t aBase = (size_t)blockIdx.x * BM * DDIM;
  const size_t bBase = (size_t)blockIdx.y * BN * DDIM;

  f32x4 acc[4][4];
  #pragma unroll
  for (int a = 0; a < 4; a++)
    #pragma unroll
    for (int b = 0; b < 4; b++)
      acc[a][b] = (f32x4)(0.f);

  for (int k0 = 0; k0 < DDIM; k0 += BK) {
    // stage A and B tiles: 1024 16B-granules each, 4 per thread per matrix
    #pragma unroll
    for (int c = 0; c < 4; c++) {
      int idx = c * 256 + tid;           // granule index in tile
      int row = idx >> 3;                // 8 granules (64 bf16) per row
      int g = idx & 7;
      int sg = g ^ (row & 7);            // pre-swizzle the SOURCE granule
      load_lds16(xb + aBase + (size_t)row * DDIM + k0 + sg * 8, As + idx * 8);
      load_lds16(yb + bBase + (size_t)row * DDIM + k0 + sg * 8, Bs + idx * 8);
    }
    __syncthreads();  // compiler emits vmcnt(0) drain before barrier

    #pragma unroll
    for (int kk = 0; kk < 2; kk++) {
      bf16x8 af[4], bfr[4];
      #pragma unroll
      for (int a = 0; a < 4; a++) {
        int row = wr * 64 + a * 16 + l15;
        int gran = kk * 4 + l16;
        int off = row * BK + ((gran ^ (row & 7)) << 3);  // elements
        af[a] = *(const bf16x8*)((const char*)As + (size_t)off * 2);
      }
      #pragma unroll
      for (int b = 0; b < 4; b++) {
        int col = wc * 64 + b * 16 + l15;
        int gran = kk * 4 + l16;
        int off = col * BK + ((gran ^ (col & 7)) << 3);
        bfr[b] = *(const bf16x8*)((const char*)Bs + (size_t)off * 2);
      }
      #pragma unroll
      for (int a = 0; a < 4; a++)
        #pragma unroll
        for (int b = 0; b < 4; b++)
          acc[a][b] = __builtin_amdgcn_mfma_f32_16x16x32_bf16(af[a], bfr[b], acc[a][b], 0, 0, 0);
    }
    __syncthreads();
  }

  // ---- fused epilogue ----
  const float cut_c = fminf(fmaxf(cutoff[0], 0.f), 1000.f);
  const float ph = phi[0];
  const int rowBase = blockIdx.x * BM + wr * 64;
  const int colBase = blockIdx.y * BN + wc * 64;

  float sq_i[4][4], sx_i[4][4];
  #pragma unroll
  for (int a = 0; a < 4; a++)
    #pragma unroll
    for (int r = 0; r < 4; r++) {
      int i = rowBase + a * 16 + l16 * 4 + r;
      sq_i[a][r] = sqx[i];
      sx_i[a][r] = ssx[i];
    }
  float sq_j[4], sy_j[4];
  #pragma unroll
  for (int b = 0; b < 4; b++) {
    int j = colBase + b * 16 + l15;
    sq_j[b] = sqy[j];
    sy_j[b] = ssy[j];
  }

  const float L2E = 1.4426950408889634f;
  #pragma unroll
  for (int a = 0; a < 4; a++)
    #pragma unroll
    for (int b = 0; b < 4; b++)
      #pragma unroll
      for (int r = 0; r < 4; r++) {
        int i = rowBase + a * 16 + l16 * 4 + r;
        int j = colBase + b * 16 + l15;
        float dot = acc[a][b][r];
        float d = sq_i[a][r] + sq_j[b] - 2.f * dot;      // squared distance
        float s = sx_i[a][r] * sy_j[b];                  // sqrt(scale_x*scale_y)
        float res = s * __builtin_amdgcn_rcpf(s + d);    // 1/(1+d/s)
        float t = ph * (res - cut_c);
        float u = __builtin_amdgcn_exp2f(-t * L2E);      // exp(-t)
        float cm = __builtin_amdgcn_rcpf(1.f + u);       // sigmoid(t)
        out[(size_t)i * M_ROWS + j] = res * cm;
      }
}

extern "C" void kernel_launch(void* const* d_in, const int* in_sizes, int n_in,
                              void* d_out, int out_size, void* d_ws, size_t ws_size,
                              hipStream_t stream) {
  const float* x       = (const float*)d_in[0];
  const float* y       = (const float*)d_in[1];
  const float* samp_x  = (const float*)d_in[2];
  const float* samp_y  = (const float*)d_in[3];
  const float* scale   = (const float*)d_in[4];
  const float* cutoff  = (const float*)d_in[5];
  const float* phi     = (const float*)d_in[6];
  float* out = (float*)d_out;

  char* p = (char*)d_ws;
  ushort* xb = (ushort*)p; p += (size_t)N_ROWS * DDIM * 2;
  ushort* yb = (ushort*)p; p += (size_t)M_ROWS * DDIM * 2;
  float* sqx = (float*)p;  p += (size_t)N_ROWS * 4;
  float* sqy = (float*)p;  p += (size_t)M_ROWS * 4;
  float* ssx = (float*)p;  p += (size_t)N_ROWS * 4;
  float* ssy = (float*)p;  p += (size_t)M_ROWS * 4;

  prep_kernel<<<N_ROWS + M_ROWS, 256, 0, stream>>>(
      x, y, samp_x, samp_y, scale, xb, yb, sqx, sqy, ssx, ssy);

  dim3 grid(N_ROWS / BM, M_ROWS / BN);
  cauchy_gemm<<<grid, 256, 0, stream>>>(
      xb, yb, sqx, sqy, ssx, ssy, cutoff, phi, out);
}